// Round 1
// baseline (124.984 us; speedup 1.0000x reference)
//
#include <hip/hip_runtime.h>
#include <math.h>

#define T_DIM 2048
#define C_DIM 1024
#define H_NUM 16
#define HD_DIM 64
#define K_LCP 8
#define NEG_VAL -1.0e9f

typedef __bf16 bf16;
typedef __bf16 bf16x4 __attribute__((ext_vector_type(4)));
typedef __bf16 bf16x8 __attribute__((ext_vector_type(8)));
typedef float f32x4 __attribute__((ext_vector_type(4)));
typedef unsigned long long u64;

// ---- A: conv+qdkd (0..511), xpartial+flagzero (512..543), transposes (544..1567)
__global__ __launch_bounds__(256) void fused_a(
    const float* __restrict__ x, const float* __restrict__ Wdq,
    const float* __restrict__ Wdk, const float* __restrict__ Wq,
    const float* __restrict__ Wk, const float* __restrict__ Wv,
    const float* __restrict__ Wproj, bf16* __restrict__ xb,
    float* __restrict__ qd, float* __restrict__ kd, float* __restrict__ partial,
    int* __restrict__ flags, bf16* __restrict__ wqt, bf16* __restrict__ wkt,
    bf16* __restrict__ wvt, bf16* __restrict__ wpt) {
  __shared__ bf16 tile[64][65];
  const int vb = blockIdx.x;
  const int tid = threadIdx.x;
  if (vb < 512) {  // convert + qd/kd, one wave per row
    const int wave = tid >> 6, lane = tid & 63;
    const int t = vb * 4 + wave;
    const float* xp = x + (size_t)t * C_DIM;
    bf16* xbp = xb + (size_t)t * C_DIM;
    float aq[8] = {}, ak[8] = {};
#pragma unroll
    for (int i = 0; i < 16; ++i) {
      const int c = i * 64 + lane;
      float xv = xp[c];
      xbp[c] = (bf16)xv;
      float4 wq0 = *(const float4*)(Wdq + (size_t)c * K_LCP);
      float4 wq1 = *(const float4*)(Wdq + (size_t)c * K_LCP + 4);
      float4 wk0 = *(const float4*)(Wdk + (size_t)c * K_LCP);
      float4 wk1 = *(const float4*)(Wdk + (size_t)c * K_LCP + 4);
      aq[0] = fmaf(xv, wq0.x, aq[0]); aq[1] = fmaf(xv, wq0.y, aq[1]);
      aq[2] = fmaf(xv, wq0.z, aq[2]); aq[3] = fmaf(xv, wq0.w, aq[3]);
      aq[4] = fmaf(xv, wq1.x, aq[4]); aq[5] = fmaf(xv, wq1.y, aq[5]);
      aq[6] = fmaf(xv, wq1.z, aq[6]); aq[7] = fmaf(xv, wq1.w, aq[7]);
      ak[0] = fmaf(xv, wk0.x, ak[0]); ak[1] = fmaf(xv, wk0.y, ak[1]);
      ak[2] = fmaf(xv, wk0.z, ak[2]); ak[3] = fmaf(xv, wk0.w, ak[3]);
      ak[4] = fmaf(xv, wk1.x, ak[4]); ak[5] = fmaf(xv, wk1.y, ak[5]);
      ak[6] = fmaf(xv, wk1.z, ak[6]); ak[7] = fmaf(xv, wk1.w, ak[7]);
    }
#pragma unroll
    for (int j = 0; j < 8; ++j) {
#pragma unroll
      for (int off = 32; off >= 1; off >>= 1) {
        aq[j] += __shfl_xor(aq[j], off);
        ak[j] += __shfl_xor(ak[j], off);
      }
    }
    if (lane == 0) {
      *(float4*)(qd + (size_t)t * K_LCP) = make_float4(aq[0], aq[1], aq[2], aq[3]);
      *(float4*)(qd + (size_t)t * K_LCP + 4) = make_float4(aq[4], aq[5], aq[6], aq[7]);
      *(float4*)(kd + (size_t)t * K_LCP) = make_float4(ak[0], ak[1], ak[2], ak[3]);
      *(float4*)(kd + (size_t)t * K_LCP + 4) = make_float4(ak[4], ak[5], ak[6], ak[7]);
    }
  } else if (vb < 544) {  // xpartial arm (+ flag zeroing in first block)
    const int b = vb - 512;
    if (b == 0 && tid < 112) flags[tid] = 0;
    f32x4 s = {0.f, 0.f, 0.f, 0.f};
    for (int r = 0; r < 64; ++r)
      s += ((const f32x4*)(x + (size_t)(b * 64 + r) * C_DIM))[tid];
    ((f32x4*)(partial + (size_t)b * C_DIM))[tid] = s;
  } else {  // transpose+convert weights (unconditional)
    const int idx = vb - 544;
    const int z = idx >> 8;
    const float* W = (z == 0) ? Wq : (z == 1) ? Wk : (z == 2) ? Wv : Wproj;
    bf16* O = (z == 0) ? wqt : (z == 1) ? wkt : (z == 2) ? wvt : wpt;
    const int rem = idx & 255;
    const int bk = (rem >> 4) * 64;
    const int bn = (rem & 15) * 64;
    const int r = tid >> 2;
    const int c0 = (tid & 3) * 16;
    const float* src = W + (size_t)(bk + r) * C_DIM + bn + c0;
#pragma unroll
    for (int t = 0; t < 16; t += 4) {
      float4 f = *(const float4*)(src + t);
      tile[r][c0 + t + 0] = (bf16)f.x;
      tile[r][c0 + t + 1] = (bf16)f.y;
      tile[r][c0 + t + 2] = (bf16)f.z;
      tile[r][c0 + t + 3] = (bf16)f.w;
    }
    __syncthreads();
    bf16* dst = O + (size_t)(bn + r) * C_DIM + bk + c0;
#pragma unroll
    for (int t = 0; t < 16; ++t) dst[t] = tile[c0 + t][r];
  }
}

// ---- B: tilemask + maskbits (ballot) + atomic need flags (0..127), vmean (128..143)
__global__ __launch_bounds__(256) void fused_b(
    const float* __restrict__ qd, const float* __restrict__ kd,
    const float* __restrict__ partial, const float* __restrict__ Wv,
    int* __restrict__ tilemask, int* __restrict__ allmask,
    u64* __restrict__ maskbits, float* __restrict__ vmean,
    int* __restrict__ qneed, int* __restrict__ kneed, int* __restrict__ vneed,
    int* __restrict__ pneed) {
  const int tid = threadIdx.x;
  if (blockIdx.x >= 128) {  // vmean = (colmean x) @ Wv
    __shared__ float xm[C_DIM];
    __shared__ float red[4][64];
    const int blk = blockIdx.x - 128;
    f32x4 s = {0.f, 0.f, 0.f, 0.f};
    for (int g = 0; g < 32; ++g) s += ((const f32x4*)partial)[g * 256 + tid];
    s *= (1.0f / 2048.0f);
    *(f32x4*)&xm[tid * 4] = s;
    __syncthreads();
    const int j = blk * 64 + (tid & 63);
    const int p = tid >> 6;
    float acc = 0.f;
    for (int c = p * 256; c < p * 256 + 256; ++c)
      acc = fmaf(xm[c], Wv[(size_t)c * C_DIM + j], acc);
    red[p][tid & 63] = acc;
    __syncthreads();
    if (tid < 64)
      vmean[blk * 64 + tid] =
          (red[0][tid] + red[1][tid]) + (red[2][tid] + red[3][tid]);
    return;
  }
  const int qb = blockIdx.x;
  __shared__ float qds[16][K_LCP];
  __shared__ int tm[32];
  const int wv = tid >> 6, lane = tid & 63;
  if (tid < 32) tm[tid] = 0;
  if (tid < 16 * K_LCP)
    qds[tid >> 3][tid & 7] = qd[(size_t)(qb * 16 + (tid >> 3)) * K_LCP + (tid & 7)];
  __syncthreads();
  // each wave covers one aligned 64-key group per iteration -> __ballot IS the mask word
  for (int it = 0; it < 8; ++it) {
    const int key = it * 256 + wv * 64 + lane;
    float kv[K_LCP];
    *(float4*)&kv[0] = *(const float4*)(kd + (size_t)key * K_LCP);
    *(float4*)&kv[4] = *(const float4*)(kd + (size_t)key * K_LCP + 4);
    const int grp = it * 4 + wv;
    u64 anyb = 0ull;
#pragma unroll
    for (int ql = 0; ql < 16; ++ql) {
      const int qg = qb * 16 + ql;
      // lcp >= 7  <=>  first 7 elements equal (prefix property); causal folded in
      bool p = (key <= qg) & (qds[ql][0] == kv[0]) & (qds[ql][1] == kv[1]) &
               (qds[ql][2] == kv[2]) & (qds[ql][3] == kv[3]) &
               (qds[ql][4] == kv[4]) & (qds[ql][5] == kv[5]) &
               (qds[ql][6] == kv[6]);
      u64 b = __ballot(p);
      anyb |= b;
      if (lane == 0) maskbits[(size_t)qg * 32 + grp] = b;
    }
    if (lane == 0 && anyb) tm[grp] = 1;
  }
  __syncthreads();
  int anytm = 0;
#pragma unroll
  for (int i = 0; i < 32; ++i) anytm |= tm[i];
  if (tid < 32) tilemask[qb * 32 + tid] = tm[tid];
  if (tid == 0) allmask[qb] = !anytm;
  if (anytm) {  // flags pre-zeroed in launch A; device-scope atomics
    if (tid < 32) {
      if (tm[tid]) atomicOr(&kneed[tid >> 1], 1);
      atomicOr(&vneed[tid >> 1], 1);
    }
    if (tid == 0) {
      atomicOr(&qneed[qb >> 3], 1);
      atomicOr(&pneed[qb >> 2], 1);
    }
  }
}

// ---- MFMA GEMM body (m97 structure) --------------------------------------------
template <int TMt, int MI, int NA>
__device__ void gemm_body(bf16* As, bf16* Bs, const bf16* A, const bf16* Bt,
                          void* Cv, int bx, int by, int z, int mode,
                          const float* cosT, const float* sinT, float* vtsum) {
  const int tid = threadIdx.x;
  const int Kd = C_DIM, N = C_DIM;
  const int bm = by * TMt;
  const int bn = bx * 128;
  const int wave = tid >> 6, lane = tid & 63;
  const int lr = lane >> 2;
  const int lc = (lane & 3) * 8;
  bf16* gA = (bf16*)(A + (size_t)(bm + wave * 16 * NA + lr) * Kd + lc);
  bf16* gB = (bf16*)(Bt + (size_t)(bn + wave * 32 + lr) * Kd + lc);
  bf16* lA = As + wave * 512 * NA;
  bf16* lB = Bs + wave * 1024;
  const int wr = (wave >> 1) * (MI * 16);
  const int wc = (wave & 1) * 64;
  const int fm = lane & 15;
  const int fk_ = (lane >> 4) * 8;

  f32x4 acc[MI][4] = {};
  for (int k0 = 0; k0 < Kd; k0 += 32) {
    __syncthreads();
#pragma unroll
    for (int u = 0; u < NA; ++u)
      __builtin_amdgcn_global_load_lds(
          (__attribute__((address_space(1))) void*)(gA + (size_t)u * 16 * Kd + k0),
          (__attribute__((address_space(3))) void*)(lA + u * 512), 16, 0, 0);
#pragma unroll
    for (int u = 0; u < 2; ++u)
      __builtin_amdgcn_global_load_lds(
          (__attribute__((address_space(1))) void*)(gB + (size_t)u * 16 * Kd + k0),
          (__attribute__((address_space(3))) void*)(lB + u * 512), 16, 0, 0);
    __syncthreads();
    bf16x8 af[MI], bfr[4];
#pragma unroll
    for (int i = 0; i < MI; ++i)
      af[i] = *(const bf16x8*)(As + (size_t)(wr + i * 16 + fm) * 32 + fk_);
#pragma unroll
    for (int j = 0; j < 4; ++j)
      bfr[j] = *(const bf16x8*)(Bs + (size_t)(wc + j * 16 + fm) * 32 + fk_);
#pragma unroll
    for (int i = 0; i < MI; ++i)
#pragma unroll
      for (int j = 0; j < 4; ++j)
        acc[i][j] = __builtin_amdgcn_mfma_f32_16x16x32_bf16(af[i], bfr[j],
                                                            acc[i][j], 0, 0, 0);
  }
  const int cq = (lane >> 4) * 4;
  if (mode && z < 2) {  // q/k: fused RoPE + RMS epilogue, bf16 out
    bf16* C = (bf16*)Cv;
#pragma unroll
    for (int i = 0; i < MI; ++i)
#pragma unroll
      for (int r = 0; r < 4; ++r) {
        const int t = bm + wr + i * 16 + cq + r;
        float c0 = cosT[(size_t)t * 32 + fm], s0 = sinT[(size_t)t * 32 + fm];
        float c1 = cosT[(size_t)t * 32 + 16 + fm];
        float s1 = sinT[(size_t)t * 32 + 16 + fm];
        float a0 = acc[i][0][r], a1 = acc[i][1][r];
        float a2 = acc[i][2][r], a3 = acc[i][3][r];
        float o0 = a0 * c0 - a2 * s0, o2 = a0 * s0 + a2 * c0;
        float o1 = a1 * c1 - a3 * s1, o3 = a1 * s1 + a3 * c1;
        float ss = o0 * o0 + o1 * o1 + o2 * o2 + o3 * o3;
        ss += __shfl_xor(ss, 1);
        ss += __shfl_xor(ss, 2);
        ss += __shfl_xor(ss, 4);
        ss += __shfl_xor(ss, 8);
        float rn = 1.0f / sqrtf(ss * (1.0f / 64.0f) + 1e-6f);
        size_t base = (size_t)t * N + bn + wc + fm;
        C[base + 0] = (bf16)(o0 * rn);
        C[base + 16] = (bf16)(o1 * rn);
        C[base + 32] = (bf16)(o2 * rn);
        C[base + 48] = (bf16)(o3 * rn);
      }
  } else if (mode) {  // V: bf16 out + fused vtsum (fp32 accs)
    bf16* C = (bf16*)Cv;
#pragma unroll
    for (int i = 0; i < MI; ++i)
#pragma unroll
      for (int r = 0; r < 4; ++r) {
        size_t base = (size_t)(bm + wr + i * 16 + cq + r) * N + bn + wc + fm;
#pragma unroll
        for (int j = 0; j < 4; ++j) C[base + j * 16] = (bf16)acc[i][j][r];
      }
    const int kt = (bm + wr) >> 6;  // MI==4: wave quadrant = one 64-row kt tile
#pragma unroll
    for (int j = 0; j < 4; ++j) {
      float s = 0.f;
#pragma unroll
      for (int i = 0; i < MI; ++i)
#pragma unroll
        for (int r = 0; r < 4; ++r) s += acc[i][j][r];
      s += __shfl_xor(s, 16);
      s += __shfl_xor(s, 32);
      if ((lane >> 4) == 0)
        vtsum[(size_t)kt * C_DIM + bn + wc + j * 16 + fm] = s;
    }
  } else {  // proj: float out
    float* C = (float*)Cv;
#pragma unroll
    for (int i = 0; i < MI; ++i)
#pragma unroll
      for (int r = 0; r < 4; ++r) {
        size_t base = (size_t)(bm + wr + i * 16 + cq + r) * N + bn + wc + fm;
#pragma unroll
        for (int j = 0; j < 4; ++j) C[base + j * 16] = acc[i][j][r];
      }
  }
}

// ---- C: flagged QKV GEMM (0..383) + rowout matvec (384..399) -------------------
__global__ __launch_bounds__(256) void phase_c(
    const bf16* __restrict__ xb, const bf16* __restrict__ wqt,
    const bf16* __restrict__ wkt, const bf16* __restrict__ wvt,
    bf16* __restrict__ qB, bf16* __restrict__ kB, bf16* __restrict__ vB,
    float* __restrict__ vtsum, const float* __restrict__ cosT,
    const float* __restrict__ sinT, const int* __restrict__ qneed,
    const int* __restrict__ kneed, const int* __restrict__ vneed,
    const float* __restrict__ vmean, const float* __restrict__ Wproj,
    float* __restrict__ rowout) {
  __shared__ __align__(16) bf16 As[128 * 32];
  __shared__ __align__(16) bf16 Bs[128 * 32];
  const int vb = blockIdx.x;
  const int tid = threadIdx.x;
  if (vb < 384) {
    const int z = vb >> 7, r = vb & 127, by = r >> 3, bx = r & 7;
    const int* f = (z == 0) ? qneed : (z == 1) ? kneed : vneed;
    if (!f[by]) return;
    const bf16* Bt = (z == 0) ? wqt : (z == 1) ? wkt : wvt;
    void* C = (z == 0) ? (void*)qB : (z == 1) ? (void*)kB : (void*)vB;
    gemm_body<128, 4, 2>(As, Bs, xb, Bt, C, bx, by, z, 1, cosT, sinT, vtsum);
  } else {  // rowout = vmean @ Wproj
    __shared__ float xm[C_DIM];
    __shared__ float red[4][64];
    const int blk = vb - 384;
    f32x4 s = ((const f32x4*)vmean)[tid];
    *(f32x4*)&xm[tid * 4] = s;
    __syncthreads();
    const int j = blk * 64 + (tid & 63);
    const int p = tid >> 6;
    float acc = 0.f;
    for (int c = p * 256; c < p * 256 + 256; ++c)
      acc = fmaf(xm[c], Wproj[(size_t)c * C_DIM + j], acc);
    red[p][tid & 63] = acc;
    __syncthreads();
    if (tid < 64)
      rowout[blk * 64 + tid] =
          (red[0][tid] + red[1][tid]) + (red[2][tid] + red[3][tid]);
  }
}

// ---- MFMA flash attention: 64 queries x 1 head per block, 4 waves x 16q --------
__device__ inline void write_vmean16(const float* vmp, bf16* yp) {
  f32x4 a0 = ((const f32x4*)vmp)[0];
  f32x4 a1 = ((const f32x4*)vmp)[1];
  f32x4 a2 = ((const f32x4*)vmp)[2];
  f32x4 a3 = ((const f32x4*)vmp)[3];
  bf16x8 o0 = {(bf16)a0[0], (bf16)a0[1], (bf16)a0[2], (bf16)a0[3],
               (bf16)a1[0], (bf16)a1[1], (bf16)a1[2], (bf16)a1[3]};
  bf16x8 o1 = {(bf16)a2[0], (bf16)a2[1], (bf16)a2[2], (bf16)a2[3],
               (bf16)a3[0], (bf16)a3[1], (bf16)a3[2], (bf16)a3[3]};
  *(bf16x8*)yp = o0;
  *(bf16x8*)(yp + 8) = o1;
}

__global__ __launch_bounds__(256) void attn2(
    const bf16* __restrict__ q, const bf16* __restrict__ k,
    const bf16* __restrict__ v, const float* __restrict__ vtsum,
    const float* __restrict__ vmean, const u64* __restrict__ maskbits,
    const int* __restrict__ tilemask, const int* __restrict__ allmask,
    const int* __restrict__ pneed, bf16* __restrict__ y) {
  const int h = blockIdx.y;
  const int q0 = blockIdx.x * 64;
  const int tid = threadIdx.x;
  const int wv = tid >> 6;
  const int lane = tid & 63;
  const int qb0 = q0 >> 4;

  const int a0 = allmask[qb0 + 0], a1 = allmask[qb0 + 1];
  const int a2 = allmask[qb0 + 2], a3 = allmask[qb0 + 3];
  const int pn = pneed[q0 >> 6];
  if (a0 & a1 & a2 & a3) {  // whole block degenerate -> vmean rows
    if (pn) {
      const int row = tid >> 2, d0 = (tid & 3) * 16;
      write_vmean16(vmean + h * HD_DIM + d0,
                    y + (size_t)(q0 + row) * C_DIM + h * HD_DIM + d0);
    }
    return;
  }
  const int w_active = !((wv == 0) ? a0 : (wv == 1) ? a1 : (wv == 2) ? a2 : a3);

  __shared__ __align__(16) bf16 vsT[64][72];      // V^T tile: [d][key]
  __shared__ __align__(16) bf16 ps[4][16][72];    // per-wave P: [q][key]
  __shared__ int tmS[4][32];
  if (tid < 128)
    tmS[tid >> 5][tid & 31] = tilemask[(size_t)(qb0 + (tid >> 5)) * 32 + (tid & 31)];

  // degenerate wave inside a live block: write vmean rows now, then barrier-only
  if (!w_active && pn) {
    const int row = wv * 16 + (lane >> 2), d0 = (lane & 3) * 16;
    write_vmean16(vmean + h * HD_DIM + d0,
                  y + (size_t)(q0 + row) * C_DIM + h * HD_DIM + d0);
  }

  const int fm = lane & 15;
  const int fk = (lane >> 4) * 8;
  bf16x8 aq0 = {}, aq1 = {};
  if (w_active) {  // Q A-fragments live in registers for the whole kernel
    const bf16* qp = q + (size_t)(q0 + wv * 16 + fm) * C_DIM + h * HD_DIM;
    aq0 = *(const bf16x8*)(qp + fk);
    aq1 = *(const bf16x8*)(qp + 32 + fk);
  }
  __syncthreads();

  float m[4] = {-INFINITY, -INFINITY, -INFINITY, -INFINITY};
  float l[4] = {0.f, 0.f, 0.f, 0.f};
  f32x4 out[4] = {};

  for (int kt = 0; kt < T_DIM / 64; ++kt) {
    const int need = tmS[0][kt] | tmS[1][kt] | tmS[2][kt] | tmS[3][kt];
    const int k0 = kt * 64;
    if (need) {  // cooperative V^T staging; conflict-free ds writes (d uniform/instr)
      __syncthreads();
      {
        const int row = tid & 63, d0 = (tid >> 6) * 16;
        const bf16* vp = v + (size_t)(k0 + row) * C_DIM + h * HD_DIM + d0;
        bf16x8 v0 = *(const bf16x8*)(vp);
        bf16x8 v1 = *(const bf16x8*)(vp + 8);
#pragma unroll
        for (int i = 0; i < 8; ++i) vsT[d0 + i][row] = v0[i];
#pragma unroll
        for (int i = 0; i < 8; ++i) vsT[d0 + 8 + i][row] = v1[i];
      }
      __syncthreads();
    }
    if (!w_active) continue;
    if (tmS[wv][kt]) {
      // packed mask words for this wave's 4 query rows, pre-shifted by fm
      u64 mwr[4];
#pragma unroll
      for (int r = 0; r < 4; ++r)
        mwr[r] = maskbits[(size_t)(q0 + wv * 16 + (lane >> 4) * 4 + r) * 32 + kt] >> fm;
      // QK^T: K fragments straight from global (one 128B line per row, L1-shared)
      f32x4 s[4] = {};
#pragma unroll
      for (int j = 0; j < 4; ++j) {
        const bf16* kp = k + (size_t)(k0 + j * 16 + fm) * C_DIM + h * HD_DIM;
        bf16x8 bk0 = *(const bf16x8*)(kp + fk);
        bf16x8 bk1 = *(const bf16x8*)(kp + 32 + fk);
        s[j] = __builtin_amdgcn_mfma_f32_16x16x32_bf16(aq0, bk0, s[j], 0, 0, 0);
        s[j] = __builtin_amdgcn_mfma_f32_16x16x32_bf16(aq1, bk1, s[j], 0, 0, 0);
      }
      // mask + scale + online softmax (reductions within 16-lane groups)
      float xv[4][4];
      float tmax[4] = {NEG_VAL, NEG_VAL, NEG_VAL, NEG_VAL};
#pragma unroll
      for (int j = 0; j < 4; ++j)
#pragma unroll
        for (int r = 0; r < 4; ++r) {
          float val = ((mwr[r] >> (16 * j)) & 1ull) ? s[j][r] * 0.125f : NEG_VAL;
          xv[j][r] = val;
          tmax[r] = fmaxf(tmax[r], val);
        }
#pragma unroll
      for (int r = 0; r < 4; ++r) {
#pragma unroll
        for (int off = 1; off < 16; off <<= 1)
          tmax[r] = fmaxf(tmax[r], __shfl_xor(tmax[r], off));
      }
      float alpha[4], lsum[4] = {0.f, 0.f, 0.f, 0.f};
#pragma unroll
      for (int r = 0; r < 4; ++r) {
        float mn = fmaxf(m[r], tmax[r]);
        alpha[r] = __expf(m[r] - mn);
        m[r] = mn;
      }
#pragma unroll
      for (int j = 0; j < 4; ++j)
#pragma unroll
        for (int r = 0; r < 4; ++r) {
          float p = __expf(xv[j][r] - m[r]);
          lsum[r] += p;
          ps[wv][(lane >> 4) * 4 + r][j * 16 + fm] = (bf16)p;
        }
#pragma unroll
      for (int r = 0; r < 4; ++r) {
#pragma unroll
        for (int off = 1; off < 16; off <<= 1) lsum[r] += __shfl_xor(lsum[r], off);
        l[r] = l[r] * alpha[r] + lsum[r];
      }
#pragma unroll
      for (int jd = 0; jd < 4; ++jd)
#pragma unroll
        for (int r = 0; r < 4; ++r) out[jd][r] *= alpha[r];
      // PV: P re-fragmented through per-wave LDS (intra-wave, lgkmcnt-ordered)
      bf16x8 pa0 = *(const bf16x8*)&ps[wv][fm][fk];
      bf16x8 pa1 = *(const bf16x8*)&ps[wv][fm][32 + fk];
#pragma unroll
      for (int jd = 0; jd < 4; ++jd) {
        bf16x8 bv0 = *(const bf16x8*)&vsT[jd * 16 + fm][fk];
        bf16x8 bv1 = *(const bf16x8*)&vsT[jd * 16 + fm][32 + fk];
        out[jd] = __builtin_amdgcn_mfma_f32_16x16x32_bf16(pa0, bv0, out[jd], 0, 0, 0);
        out[jd] = __builtin_amdgcn_mfma_f32_16x16x32_bf16(pa1, bv1, out[jd], 0, 0, 0);
      }
    } else {
      // fully-masked tile: uniform contribution while no real tile seen yet
      int needu = (m[0] <= NEG_VAL) | (m[1] <= NEG_VAL) | (m[2] <= NEG_VAL) |
                  (m[3] <= NEG_VAL);
      if (needu) {
#pragma unroll
        for (int jd = 0; jd < 4; ++jd) {
          float vt = vtsum[(size_t)kt * C_DIM + h * HD_DIM + jd * 16 + fm];
#pragma unroll
          for (int r = 0; r < 4; ++r)
            if (m[r] <= NEG_VAL) out[jd][r] += vt;
        }
#pragma unroll
        for (int r = 0; r < 4; ++r)
          if (m[r] <= NEG_VAL) {
            m[r] = NEG_VAL;
            l[r] += 64.f;
          }
      }
    }
  }

  if (w_active) {
#pragma unroll
    for (int r = 0; r < 4; ++r) {
      float inv_l = 1.0f / l[r];
      bf16* yp = y + (size_t)(q0 + wv * 16 + (lane >> 4) * 4 + r) * C_DIM +
                 h * HD_DIM + fm;
#pragma unroll
      for (int jd = 0; jd < 4; ++jd) yp[jd * 16] = (bf16)(out[jd][r] * inv_l);
    }
  }
}

// ---- E: flagged proj GEMM (0..255) + bcast (256..511) --------------------------
__global__ __launch_bounds__(256) void phase_e(
    const bf16* __restrict__ yb, const bf16* __restrict__ wpt,
    float* __restrict__ out, const int* __restrict__ pneed,
    const float* __restrict__ rowout, const float* __restrict__ cosT,
    const float* __restrict__ sinT) {
  __shared__ __align__(16) bf16 As[64 * 32];
  __shared__ __align__(16) bf16 Bs[128 * 32];
  const int vb = blockIdx.x;
  if (vb < 256) {
    const int by = vb >> 3, bx = vb & 7;
    if (!pneed[by]) return;
    gemm_body<64, 2, 1>(As, Bs, yb, wpt, (void*)out, bx, by, 2, 0, cosT, sinT,
                        nullptr);
  } else {  // broadcast rowout into fully-all-masked 64-row out blocks
    const int b = vb - 256;
    f32x4 v = ((const f32x4*)rowout)[threadIdx.x];
#pragma unroll
    for (int r = 0; r < 8; ++r) {
      const int row = b * 8 + r;
      if (pneed[row >> 6]) continue;
      ((f32x4*)(out + (size_t)row * C_DIM))[threadIdx.x] = v;
    }
  }
}

extern "C" void kernel_launch(void* const* d_in, const int* in_sizes, int n_in,
                              void* d_out, int out_size, void* d_ws, size_t ws_size,
                              hipStream_t stream) {
  const float* x = (const float*)d_in[0];
  const float* cosT = (const float*)d_in[1];
  const float* sinT = (const float*)d_in[2];
  const float* Wq = (const float*)d_in[3];
  const float* Wk = (const float*)d_in[4];
  const float* Wv = (const float*)d_in[5];
  const float* Wproj = (const float*)d_in[6];
  const float* Wdq = (const float*)d_in[7];
  const float* Wdk = (const float*)d_in[8];
  float* out = (float*)d_out;

  char* ws = (char*)d_ws;
  const size_t TC2 = (size_t)T_DIM * C_DIM * 2;
  const size_t CC2 = (size_t)C_DIM * C_DIM * 2;
  bf16* xb = (bf16*)(ws + 0);
  bf16* wqt = (bf16*)(ws + TC2);
  bf16* wkt = (bf16*)(ws + TC2 + CC2);
  bf16* wvt = (bf16*)(ws + TC2 + 2 * CC2);
  bf16* wpt = (bf16*)(ws + TC2 + 3 * CC2);
  bf16* qB = (bf16*)(ws + TC2 + 4 * CC2);
  bf16* kB = (bf16*)(ws + 2 * TC2 + 4 * CC2);
  bf16* vB = (bf16*)(ws + 3 * TC2 + 4 * CC2);
  char* p2 = ws + 4 * TC2 + 4 * CC2;
  float* qd = (float*)p2;        p2 += (size_t)T_DIM * K_LCP * 4;
  float* kd = (float*)p2;        p2 += (size_t)T_DIM * K_LCP * 4;
  float* vtsum = (float*)p2;     p2 += 32 * C_DIM * 4;
  float* vmean = (float*)p2;     p2 += C_DIM * 4;
  float* partial = (float*)p2;   p2 += 32 * C_DIM * 4;
  float* rowout = (float*)p2;    p2 += C_DIM * 4;
  int* tilemask = (int*)p2;      p2 += (T_DIM / 16) * 32 * 4;
  int* allmask = (int*)p2;       p2 += (T_DIM / 16) * 4;
  u64* maskbits = (u64*)p2;      p2 += (size_t)T_DIM * 32 * 8;
  // contiguous flag block (zeroed as 112 ints by fused_a; 80 used)
  int* qneed = (int*)p2;         p2 += 16 * 4;
  int* kneed = (int*)p2;         p2 += 16 * 4;
  int* vneed = (int*)p2;         p2 += 16 * 4;
  int* pneed = (int*)p2;         p2 += 32 * 4;
  bf16* yb = xb;  // x (bf16) is dead after the QKV GEMM

  fused_a<<<1568, 256, 0, stream>>>(x, Wdq, Wdk, Wq, Wk, Wv, Wproj, xb, qd, kd,
                                    partial, qneed, wqt, wkt, wvt, wpt);
  fused_b<<<144, 256, 0, stream>>>(qd, kd, partial, Wv, tilemask, allmask,
                                   maskbits, vmean, qneed, kneed, vneed, pneed);
  phase_c<<<400, 256, 0, stream>>>(xb, wqt, wkt, wvt, qB, kB, vB, vtsum, cosT,
                                   sinT, qneed, kneed, vneed, vmean, Wproj,
                                   rowout);
  attn2<<<dim3(T_DIM / 64, H_NUM), 256, 0, stream>>>(
      qB, kB, vB, vtsum, vmean, maskbits, tilemask, allmask, pneed, yb);
  phase_e<<<512, 256, 0, stream>>>(yb, wpt, out, pneed, rowout, cosT, sinT);
}